// Round 2
// baseline (2653.297 us; speedup 1.0000x reference)
//
#include <hip/hip_runtime.h>
#include <hip/hip_bf16.h>

typedef __bf16 v8bf __attribute__((ext_vector_type(8)));
typedef float  v4f  __attribute__((ext_vector_type(4)));

__device__ __forceinline__ v8bf zero8() {
    v8bf r;
#pragma unroll
    for (int i = 0; i < 8; ++i) r[i] = (__bf16)0.f;
    return r;
}
__device__ __forceinline__ v4f zero4() { v4f r; r[0]=r[1]=r[2]=r[3]=0.f; return r; }

__device__ __forceinline__ v8bf load8bf(const __bf16* p) { return *(const v8bf*)p; }

// load 8 fp32, round to bf16 fragment
__device__ __forceinline__ v8bf load8f(const float* p) {
    const float4 x = ((const float4*)p)[0];
    const float4 y = ((const float4*)p)[1];
    v8bf r;
    r[0]=(__bf16)x.x; r[1]=(__bf16)x.y; r[2]=(__bf16)x.z; r[3]=(__bf16)x.w;
    r[4]=(__bf16)y.x; r[5]=(__bf16)y.y; r[6]=(__bf16)y.z; r[7]=(__bf16)y.w;
    return r;
}
__device__ __forceinline__ float silu_f(float x) { return x / (1.f + __expf(-x)); }

// ---------------- weight transpose: src fp32 [K][N] -> dst bf16 [N][K] ----------------
__global__ __launch_bounds__(256) void transpose_w(const float* __restrict__ s,
                                                   __bf16* __restrict__ d, int K, int N) {
    int idx = blockIdx.x * 256 + threadIdx.x;
    if (idx < K * N) {
        int k = idx / N, n = idx - k * N;
        d[n * K + k] = (__bf16)s[idx];
    }
}

// ---------------- scatter: v[i[e]] += e2[e]  (fp32 atomics) ----------------
__global__ __launch_bounds__(256) void scatter_e2(const float* __restrict__ e2,
                                                  const int* __restrict__ idx,
                                                  float* __restrict__ v, int total4) {
    int gid = blockIdx.x * 256 + threadIdx.x;
    if (gid >= total4) return;                    // total4 = E*128/4
    int e = gid >> 5, c4 = (gid & 31) * 4;        // 32 float4 per row
    float4 x = ((const float4*)e2)[gid];
    float* dst = v + (size_t)idx[e] * 128 + c4;
    atomicAdd(dst + 0, x.x);
    atomicAdd(dst + 1, x.y);
    atomicAdd(dst + 2, x.z);
    atomicAdd(dst + 3, x.w);
}

// ---------------- v_hull = v @ w_hull  [M,128]x[128,128] -> bf16 ----------------
__global__ __launch_bounds__(256) void gemm_vhull(const float* __restrict__ v,
                                                  const __bf16* __restrict__ wT,
                                                  __bf16* __restrict__ out, int M) {
    int wave = threadIdx.x >> 6, lane = threadIdx.x & 63;
    int q = lane >> 4, l16 = lane & 15;
    int m0 = blockIdx.x * 64 + wave * 16;
    v4f acc[8];
#pragma unroll
    for (int i = 0; i < 8; ++i) acc[i] = zero4();
    int arow = m0 + l16; if (arow >= M) arow = M - 1;
#pragma unroll
    for (int kt = 0; kt < 4; ++kt) {
        v8bf a = load8f(v + (size_t)arow * 128 + kt * 32 + q * 8);
#pragma unroll
        for (int nt = 0; nt < 8; ++nt) {
            v8bf b = load8bf(wT + (size_t)(nt * 16 + l16) * 128 + kt * 32 + q * 8);
            acc[nt] = __builtin_amdgcn_mfma_f32_16x16x32_bf16(a, b, acc[nt], 0, 0, 0);
        }
    }
#pragma unroll
    for (int nt = 0; nt < 8; ++nt)
#pragma unroll
        for (int r = 0; r < 4; ++r) {
            int row = m0 + q * 4 + r;
            if (row < M) out[(size_t)row * 128 + nt * 16 + l16] = (__bf16)acc[nt][r];
        }
}

// ---------------- hull edges: Wh = mlp(fea); oh[i_] += vhull[j_]*Wh ----------------
__global__ __launch_bounds__(256) void hull_edge(const float* __restrict__ fea,
                                                 const int* __restrict__ jidx,
                                                 const int* __restrict__ iidx,
                                                 const __bf16* __restrict__ w0T,
                                                 const float* __restrict__ bias0,
                                                 const __bf16* __restrict__ w1T,
                                                 const float* __restrict__ bias1,
                                                 const __bf16* __restrict__ vhull,
                                                 float* __restrict__ oh, int EH) {
    __shared__ __bf16 hb[64][136];
    __shared__ int jb[64], ib[64];
    int t = threadIdx.x;
    int wave = t >> 6, lane = t & 63, q = lane >> 4, l16 = lane & 15;
    int r0 = blockIdx.x * 64;
    if (t < 64) {
        int e = r0 + t; if (e >= EH) e = EH - 1;
        jb[t] = jidx[e];
        ib[t] = iidx[e];
    }
    // stage 1: h = silu(fea @ w_mlp0 + b0)   K=16 (padded to 32)
    {
        int er = r0 + wave * 16 + l16; if (er >= EH) er = EH - 1;
        v8bf a = (q < 2) ? load8f(fea + (size_t)er * 16 + q * 8) : zero8();
        v4f acc[8];
#pragma unroll
        for (int i = 0; i < 8; ++i) acc[i] = zero4();
#pragma unroll
        for (int nt = 0; nt < 8; ++nt) {
            v8bf b = (q < 2) ? load8bf(w0T + (size_t)(nt * 16 + l16) * 16 + q * 8) : zero8();
            acc[nt] = __builtin_amdgcn_mfma_f32_16x16x32_bf16(a, b, acc[nt], 0, 0, 0);
        }
#pragma unroll
        for (int nt = 0; nt < 8; ++nt) {
            int col = nt * 16 + l16;
            float bc = bias0[col];
#pragma unroll
            for (int r = 0; r < 4; ++r) {
                int rowL = wave * 16 + q * 4 + r;
                hb[rowL][col] = (__bf16)silu_f(acc[nt][r] + bc);
            }
        }
    }
    __syncthreads();
    // stage 2: Wh = h @ w_mlp1 + b1, then gather-mul-scatter
    {
        v8bf af[4];
#pragma unroll
        for (int kt = 0; kt < 4; ++kt)
            af[kt] = *(const v8bf*)&hb[wave * 16 + l16][kt * 32 + q * 8];
        v4f acc[8];
#pragma unroll
        for (int i = 0; i < 8; ++i) acc[i] = zero4();
#pragma unroll
        for (int kt = 0; kt < 4; ++kt)
#pragma unroll
            for (int nt = 0; nt < 8; ++nt) {
                v8bf b = load8bf(w1T + (size_t)(nt * 16 + l16) * 128 + kt * 32 + q * 8);
                acc[nt] = __builtin_amdgcn_mfma_f32_16x16x32_bf16(af[kt], b, acc[nt], 0, 0, 0);
            }
#pragma unroll
        for (int nt = 0; nt < 8; ++nt) {
            int col = nt * 16 + l16;
            float bc = bias1[col];
#pragma unroll
            for (int r = 0; r < 4; ++r) {
                int rowL = wave * 16 + q * 4 + r;
                if (r0 + rowL < EH) {
                    float wh = acc[nt][r] + bc;
                    int j = jb[rowL], ii = ib[rowL];
                    float val = wh * (float)vhull[(size_t)j * 128 + col];
                    atomicAdd(oh + (size_t)ii * 128 + col, val);
                }
            }
        }
    }
}

// ---------------- fused per-node MLP chain ----------------
__global__ __launch_bounds__(256, 2) void node_chain(
    const float* __restrict__ v, const float* __restrict__ oh,
    const __bf16* __restrict__ w1T, const float* __restrict__ b1,
    const __bf16* __restrict__ w2T, const float* __restrict__ b2,
    const __bf16* __restrict__ wcatT, const float* __restrict__ bcat,
    const __bf16* __restrict__ wupT, const float* __restrict__ bup,
    const __bf16* __restrict__ wl0T, const float* __restrict__ bl0,
    const __bf16* __restrict__ wl1T, const float* __restrict__ bl1,
    const float* __restrict__ wout, float* __restrict__ out, int M) {
    const int LD = 392;  // bf16 elements per LDS row (padded)
    __shared__ __bf16 buf[64 * 392];
    int t = threadIdx.x, wave = t >> 6, lane = t & 63, q = lane >> 4, l16 = lane & 15;
    int m0b = blockIdx.x * 64;
    int m0 = m0b + wave * 16;
    int arow = m0 + l16; if (arow >= M) arow = M - 1;

    // load v (fp32) -> cols 0..127, float4-vectorized
#pragma unroll
    for (int k = 0; k < 8; ++k) {
        int idx = t + k * 256;            // 2048 float4 total
        int row = idx >> 5, c4 = (idx & 31) * 4;
        int gr = m0b + row; if (gr >= M) gr = M - 1;
        float4 x = ((const float4*)(v + (size_t)gr * 128))[idx & 31];
        __bf16* p = &buf[row * LD + c4];
        p[0] = (__bf16)x.x; p[1] = (__bf16)x.y; p[2] = (__bf16)x.z; p[3] = (__bf16)x.w;
    }

    // stage0: h1 = silu(oh @ w1 + b1) [64,128] -> cols 256..383
    {
        v4f acc[8];
#pragma unroll
        for (int i = 0; i < 8; ++i) acc[i] = zero4();
#pragma unroll
        for (int kt = 0; kt < 4; ++kt) {
            v8bf a = load8f(oh + (size_t)arow * 128 + kt * 32 + q * 8);
#pragma unroll
            for (int nt = 0; nt < 8; ++nt) {
                v8bf b = load8bf(w1T + (size_t)(nt * 16 + l16) * 128 + kt * 32 + q * 8);
                acc[nt] = __builtin_amdgcn_mfma_f32_16x16x32_bf16(a, b, acc[nt], 0, 0, 0);
            }
        }
#pragma unroll
        for (int nt = 0; nt < 8; ++nt) {
            int col = nt * 16 + l16;
            float bc = b1[col];
#pragma unroll
            for (int r = 0; r < 4; ++r) {
                int rowL = wave * 16 + q * 4 + r;
                buf[rowL * LD + 256 + col] = (__bf16)silu_f(acc[nt][r] + bc);
            }
        }
    }
    __syncthreads();

    // stage1: l2v = h1 @ w2 + b2 [64,256] -> cols 128..383
    {
        v8bf af[4];
#pragma unroll
        for (int kt = 0; kt < 4; ++kt)
            af[kt] = *(const v8bf*)&buf[(wave * 16 + l16) * LD + 256 + kt * 32 + q * 8];
        __syncthreads();
        v4f acc[16];
#pragma unroll
        for (int i = 0; i < 16; ++i) acc[i] = zero4();
#pragma unroll
        for (int kt = 0; kt < 4; ++kt)
#pragma unroll
            for (int nt = 0; nt < 16; ++nt) {
                v8bf b = load8bf(w2T + (size_t)(nt * 16 + l16) * 128 + kt * 32 + q * 8);
                acc[nt] = __builtin_amdgcn_mfma_f32_16x16x32_bf16(af[kt], b, acc[nt], 0, 0, 0);
            }
#pragma unroll
        for (int nt = 0; nt < 16; ++nt) {
            int col = nt * 16 + l16;
            float bc = b2[col];
#pragma unroll
            for (int r = 0; r < 4; ++r) {
                int rowL = wave * 16 + q * 4 + r;
                buf[rowL * LD + 128 + col] = (__bf16)(acc[nt][r] + bc);
            }
        }
    }
    __syncthreads();

    // stage2: u = silu([v|l2v] @ wcat + bcat)  K=384 -> cols 0..127
    {
        v8bf af[12];
#pragma unroll
        for (int kt = 0; kt < 12; ++kt)
            af[kt] = *(const v8bf*)&buf[(wave * 16 + l16) * LD + kt * 32 + q * 8];
        __syncthreads();
        v4f acc[8];
#pragma unroll
        for (int i = 0; i < 8; ++i) acc[i] = zero4();
#pragma unroll
        for (int kt = 0; kt < 12; ++kt)
#pragma unroll
            for (int nt = 0; nt < 8; ++nt) {
                v8bf b = load8bf(wcatT + (size_t)(nt * 16 + l16) * 384 + kt * 32 + q * 8);
                acc[nt] = __builtin_amdgcn_mfma_f32_16x16x32_bf16(af[kt], b, acc[nt], 0, 0, 0);
            }
#pragma unroll
        for (int nt = 0; nt < 8; ++nt) {
            int col = nt * 16 + l16;
            float bc = bcat[col];
#pragma unroll
            for (int r = 0; r < 4; ++r) {
                int rowL = wave * 16 + q * 4 + r;
                buf[rowL * LD + col] = (__bf16)silu_f(acc[nt][r] + bc);
            }
        }
    }
    __syncthreads();

    // stage3: up = u @ wup + bup [64,256] -> cols 128..383 (no act)
    {
        v8bf af[4];
#pragma unroll
        for (int kt = 0; kt < 4; ++kt)
            af[kt] = *(const v8bf*)&buf[(wave * 16 + l16) * LD + kt * 32 + q * 8];
        __syncthreads();
        v4f acc[16];
#pragma unroll
        for (int i = 0; i < 16; ++i) acc[i] = zero4();
#pragma unroll
        for (int kt = 0; kt < 4; ++kt)
#pragma unroll
            for (int nt = 0; nt < 16; ++nt) {
                v8bf b = load8bf(wupT + (size_t)(nt * 16 + l16) * 128 + kt * 32 + q * 8);
                acc[nt] = __builtin_amdgcn_mfma_f32_16x16x32_bf16(af[kt], b, acc[nt], 0, 0, 0);
            }
#pragma unroll
        for (int nt = 0; nt < 16; ++nt) {
            int col = nt * 16 + l16;
            float bc = bup[col];
#pragma unroll
            for (int r = 0; r < 4; ++r) {
                int rowL = wave * 16 + q * 4 + r;
                buf[rowL * LD + 128 + col] = (__bf16)(acc[nt][r] + bc);
            }
        }
    }
    __syncthreads();

    // stage4 + stage5: a = silu(a @ W + b) with K=256, N=256, in-place cols 128..383
#pragma unroll
    for (int s = 0; s < 2; ++s) {
        const __bf16* wT = (s == 0) ? wl0T : wl1T;
        const float* bb = (s == 0) ? bl0 : bl1;
        v8bf af[8];
#pragma unroll
        for (int kt = 0; kt < 8; ++kt)
            af[kt] = *(const v8bf*)&buf[(wave * 16 + l16) * LD + 128 + kt * 32 + q * 8];
        __syncthreads();
        v4f acc[16];
#pragma unroll
        for (int i = 0; i < 16; ++i) acc[i] = zero4();
#pragma unroll
        for (int kt = 0; kt < 8; ++kt)
#pragma unroll
            for (int nt = 0; nt < 16; ++nt) {
                v8bf b = load8bf(wT + (size_t)(nt * 16 + l16) * 256 + kt * 32 + q * 8);
                acc[nt] = __builtin_amdgcn_mfma_f32_16x16x32_bf16(af[kt], b, acc[nt], 0, 0, 0);
            }
#pragma unroll
        for (int nt = 0; nt < 16; ++nt) {
            int col = nt * 16 + l16;
            float bc = bb[col];
#pragma unroll
            for (int r = 0; r < 4; ++r) {
                int rowL = wave * 16 + q * 4 + r;
                buf[rowL * LD + 128 + col] = (__bf16)silu_f(acc[nt][r] + bc);
            }
        }
        __syncthreads();
    }

    // stage6: out = a2 @ w_out  [256,1]
    if (t < 64) {
        float s = 0.f;
#pragma unroll 8
        for (int c = 0; c < 256; ++c)
            s += (float)buf[t * LD + 128 + c] * wout[c];
        int gr = m0b + t;
        if (gr < M) out[gr] = s;
    }
}

extern "C" void kernel_launch(void* const* d_in, const int* in_sizes, int n_in,
                              void* d_out, int out_size, void* d_ws, size_t ws_size,
                              hipStream_t stream) {
    const float* e2      = (const float*)d_in[0];
    const int*   iidx    = (const int*)d_in[1];
    const float* fea     = (const float*)d_in[2];
    const int*   eih     = (const int*)d_in[3];
    const float* w_hull  = (const float*)d_in[4];
    const float* w_mlp0  = (const float*)d_in[5];
    const float* b_mlp0  = (const float*)d_in[6];
    const float* w_mlp1  = (const float*)d_in[7];
    const float* b_mlp1  = (const float*)d_in[8];
    const float* w1_hull = (const float*)d_in[9];
    const float* b1_hull = (const float*)d_in[10];
    const float* w2_hull = (const float*)d_in[11];
    const float* b2_hull = (const float*)d_in[12];
    const float* w_cat   = (const float*)d_in[13];
    const float* b_cat   = (const float*)d_in[14];
    const float* w_up    = (const float*)d_in[15];
    const float* b_up    = (const float*)d_in[16];
    const float* w_l0    = (const float*)d_in[17];
    const float* b_l0    = (const float*)d_in[18];
    const float* w_l1    = (const float*)d_in[19];
    const float* b_l1    = (const float*)d_in[20];
    const float* w_out   = (const float*)d_in[21];

    int N  = out_size;           // OC = 1
    int E  = in_sizes[0] / 128;
    int EH = in_sizes[2] / 16;

    char* ws = (char*)d_ws;
    float* v  = (float*)ws;                           // N*128 fp32
    float* oh = v + (size_t)N * 128;                  // N*128 fp32
    __bf16* vhull = (__bf16*)(oh + (size_t)N * 128);  // N*128 bf16
    __bf16* wp = vhull + (size_t)N * 128;
    __bf16* w_hullT = wp; wp += 128 * 128;
    __bf16* w0T     = wp; wp += 128 * 16;
    __bf16* w1mT    = wp; wp += 128 * 128;
    __bf16* w1hT    = wp; wp += 128 * 128;
    __bf16* w2hT    = wp; wp += 256 * 128;
    __bf16* wcatT   = wp; wp += 128 * 384;
    __bf16* wupT    = wp; wp += 256 * 128;
    __bf16* wl0T    = wp; wp += 256 * 256;
    __bf16* wl1T    = wp; wp += 256 * 256;

    // transpose all weights to bf16 [N][K]
    transpose_w<<<(128 * 128 + 255) / 256, 256, 0, stream>>>(w_hull, w_hullT, 128, 128);
    transpose_w<<<(16 * 128 + 255) / 256, 256, 0, stream>>>(w_mlp0, w0T, 16, 128);
    transpose_w<<<(128 * 128 + 255) / 256, 256, 0, stream>>>(w_mlp1, w1mT, 128, 128);
    transpose_w<<<(128 * 128 + 255) / 256, 256, 0, stream>>>(w1_hull, w1hT, 128, 128);
    transpose_w<<<(128 * 256 + 255) / 256, 256, 0, stream>>>(w2_hull, w2hT, 128, 256);
    transpose_w<<<(384 * 128 + 255) / 256, 256, 0, stream>>>(w_cat, wcatT, 384, 128);
    transpose_w<<<(128 * 256 + 255) / 256, 256, 0, stream>>>(w_up, wupT, 128, 256);
    transpose_w<<<(256 * 256 + 255) / 256, 256, 0, stream>>>(w_l0, wl0T, 256, 256);
    transpose_w<<<(256 * 256 + 255) / 256, 256, 0, stream>>>(w_l1, wl1T, 256, 256);

    // zero v and oh (adjacent)
    (void)hipMemsetAsync(v, 0, (size_t)N * 128 * 4 * 2, stream);

    int total4 = E * 128 / 4;
    scatter_e2<<<(total4 + 255) / 256, 256, 0, stream>>>(e2, iidx, v, total4);

    gemm_vhull<<<(N + 63) / 64, 256, 0, stream>>>(v, w_hullT, vhull, N);

    hull_edge<<<(EH + 63) / 64, 256, 0, stream>>>(fea, eih, eih + EH, w0T, b_mlp0,
                                                  w1mT, b_mlp1, vhull, oh, EH);

    node_chain<<<(N + 63) / 64, 256, 0, stream>>>(v, oh, w1hT, b1_hull, w2hT, b2_hull,
                                                  wcatT, b_cat, wupT, b_up,
                                                  wl0T, b_l0, wl1T, b_l1,
                                                  w_out, (float*)d_out, N);
}

// Round 3
// 1757.408 us; speedup vs baseline: 1.5098x; 1.5098x over previous
//
#include <hip/hip_runtime.h>
#include <hip/hip_bf16.h>

typedef __bf16 v8bf __attribute__((ext_vector_type(8)));
typedef float  v4f  __attribute__((ext_vector_type(4)));

__device__ __forceinline__ v8bf zero8() {
    v8bf r;
#pragma unroll
    for (int i = 0; i < 8; ++i) r[i] = (__bf16)0.f;
    return r;
}
__device__ __forceinline__ v4f zero4() { v4f r; r[0]=r[1]=r[2]=r[3]=0.f; return r; }

__device__ __forceinline__ v8bf load8bf(const __bf16* p) { return *(const v8bf*)p; }

__device__ __forceinline__ v8bf load8f(const float* p) {
    const float4 x = ((const float4*)p)[0];
    const float4 y = ((const float4*)p)[1];
    v8bf r;
    r[0]=(__bf16)x.x; r[1]=(__bf16)x.y; r[2]=(__bf16)x.z; r[3]=(__bf16)x.w;
    r[4]=(__bf16)y.x; r[5]=(__bf16)y.y; r[6]=(__bf16)y.z; r[7]=(__bf16)y.w;
    return r;
}
__device__ __forceinline__ float silu_f(float x) { return x / (1.f + __expf(-x)); }

// ---------------- weight transpose: src fp32 [K][N] -> dst bf16 [N][K] ----------------
__global__ __launch_bounds__(256) void transpose_w(const float* __restrict__ s,
                                                   __bf16* __restrict__ d, int K, int N) {
    int idx = blockIdx.x * 256 + threadIdx.x;
    if (idx < K * N) {
        int k = idx / N, n = idx - k * N;
        d[n * K + k] = (__bf16)s[idx];
    }
}

// ================= CSR construction (counting sort by destination) =================
__global__ __launch_bounds__(256) void hist_kernel(const int* __restrict__ idx,
                                                   int* __restrict__ counts, int n) {
    int g = blockIdx.x * 256 + threadIdx.x;
    if (g < n) atomicAdd(&counts[idx[g]], 1);
}

// CHUNK = 2048 per block (256 thr x 8)
__global__ __launch_bounds__(256) void scan_block_sums(const int* __restrict__ counts,
                                                       int* __restrict__ partials, int n) {
    int t = threadIdx.x, b = blockIdx.x;
    int base = b * 2048 + t * 8;
    int s = 0;
#pragma unroll
    for (int i = 0; i < 8; ++i) {
        int g = base + i;
        s += (g < n) ? counts[g] : 0;
    }
#pragma unroll
    for (int off = 32; off; off >>= 1) s += __shfl_down(s, off);
    __shared__ int wsum[4];
    if ((t & 63) == 0) wsum[t >> 6] = s;
    __syncthreads();
    if (t == 0) partials[b] = wsum[0] + wsum[1] + wsum[2] + wsum[3];
}

__global__ void scan_partials_serial(int* __restrict__ partials, int nb,
                                     int* __restrict__ row_start, int n, int total) {
    if (threadIdx.x == 0) {
        int run = 0;
        for (int i = 0; i < nb; ++i) { int t = partials[i]; partials[i] = run; run += t; }
        row_start[n] = total;
    }
}

__global__ __launch_bounds__(256) void scan_write(const int* __restrict__ counts,
                                                  const int* __restrict__ partials,
                                                  int* __restrict__ row_start,
                                                  int* __restrict__ cursor, int n) {
    int t = threadIdx.x, b = blockIdx.x;
    int base = b * 2048 + t * 8;
    int vals[8];
    int tot = 0;
#pragma unroll
    for (int i = 0; i < 8; ++i) {
        int g = base + i;
        vals[i] = (g < n) ? counts[g] : 0;
        tot += vals[i];
    }
    __shared__ int sh[256];
    sh[t] = tot;
    __syncthreads();
#pragma unroll
    for (int d = 1; d < 256; d <<= 1) {
        int v = (t >= d) ? sh[t - d] : 0;
        __syncthreads();
        sh[t] += v;
        __syncthreads();
    }
    int run = partials[b] + sh[t] - tot;
#pragma unroll
    for (int i = 0; i < 8; ++i) {
        int g = base + i;
        if (g < n) { row_start[g] = run; cursor[g] = run; }
        run += vals[i];
    }
}

__global__ __launch_bounds__(256) void rank_scatter(const int* __restrict__ idx,
                                                    int* __restrict__ cursor,
                                                    int* __restrict__ order, int n) {
    int g = blockIdx.x * 256 + threadIdx.x;
    if (g < n) {
        int d = idx[g];
        int pos = atomicAdd(&cursor[d], 1);
        order[pos] = g;
    }
}

// ================= gather-reduce: v[node] = sum of e2 rows (CSR) =================
__global__ __launch_bounds__(256) void gather_v(const float* __restrict__ e2,
                                                const int* __restrict__ order,
                                                const int* __restrict__ row_start,
                                                float* __restrict__ v, int N) {
    int t = threadIdx.x;
    int node = blockIdx.x * 2 + (t >> 7);
    int col = t & 127;
    if (node >= N) return;
    int r0 = row_start[node], r1 = row_start[node + 1];
    float acc = 0.f;
    for (int r = r0; r < r1; ++r) {
        int e = order[r];
        acc += e2[(size_t)e * 128 + col];
    }
    v[(size_t)node * 128 + col] = acc;
}

// msg rows contiguous per node
__global__ __launch_bounds__(256) void gather_oh(const float* __restrict__ msg,
                                                 const int* __restrict__ row_start,
                                                 float* __restrict__ oh, int N) {
    int t = threadIdx.x;
    int node = blockIdx.x * 2 + (t >> 7);
    int col = t & 127;
    if (node >= N) return;
    int r0 = row_start[node], r1 = row_start[node + 1];
    float acc = 0.f;
    for (int r = r0; r < r1; ++r)
        acc += msg[(size_t)r * 128 + col];
    oh[(size_t)node * 128 + col] = acc;
}

// ---------------- v_hull = v @ w_hull  [M,128]x[128,128] -> bf16 ----------------
__global__ __launch_bounds__(256) void gemm_vhull(const float* __restrict__ v,
                                                  const __bf16* __restrict__ wT,
                                                  __bf16* __restrict__ out, int M) {
    int wave = threadIdx.x >> 6, lane = threadIdx.x & 63;
    int q = lane >> 4, l16 = lane & 15;
    int m0 = blockIdx.x * 64 + wave * 16;
    v4f acc[8];
#pragma unroll
    for (int i = 0; i < 8; ++i) acc[i] = zero4();
    int arow = m0 + l16; if (arow >= M) arow = M - 1;
#pragma unroll
    for (int kt = 0; kt < 4; ++kt) {
        v8bf a = load8f(v + (size_t)arow * 128 + kt * 32 + q * 8);
#pragma unroll
        for (int nt = 0; nt < 8; ++nt) {
            v8bf b = load8bf(wT + (size_t)(nt * 16 + l16) * 128 + kt * 32 + q * 8);
            acc[nt] = __builtin_amdgcn_mfma_f32_16x16x32_bf16(a, b, acc[nt], 0, 0, 0);
        }
    }
#pragma unroll
    for (int nt = 0; nt < 8; ++nt)
#pragma unroll
        for (int r = 0; r < 4; ++r) {
            int row = m0 + q * 4 + r;
            if (row < M) out[(size_t)row * 128 + nt * 16 + l16] = (__bf16)acc[nt][r];
        }
}

// -------- hull messages in destination-sorted (CSR) order: msg[slot] = vhull[j]*Wh --------
__global__ __launch_bounds__(256) void hull_msg(const float* __restrict__ fea,
                                                const int* __restrict__ perm,
                                                const int* __restrict__ jidx,
                                                const __bf16* __restrict__ w0T,
                                                const float* __restrict__ bias0,
                                                const __bf16* __restrict__ w1T,
                                                const float* __restrict__ bias1,
                                                const __bf16* __restrict__ vhull,
                                                float* __restrict__ msg, int EH) {
    __shared__ __bf16 hb[64][136];
    __shared__ int jb[64];
    int t = threadIdx.x;
    int wave = t >> 6, lane = t & 63, q = lane >> 4, l16 = lane & 15;
    int r0 = blockIdx.x * 64;
    if (t < 64) {
        int slot = r0 + t; if (slot >= EH) slot = EH - 1;
        jb[t] = jidx[perm[slot]];
    }
    // stage 1: h = silu(fea[e] @ w_mlp0 + b0)   K=16 (padded to 32)
    {
        int slot = r0 + wave * 16 + l16; if (slot >= EH) slot = EH - 1;
        int e = perm[slot];
        v8bf a = (q < 2) ? load8f(fea + (size_t)e * 16 + q * 8) : zero8();
        v4f acc[8];
#pragma unroll
        for (int i = 0; i < 8; ++i) acc[i] = zero4();
#pragma unroll
        for (int nt = 0; nt < 8; ++nt) {
            v8bf b = (q < 2) ? load8bf(w0T + (size_t)(nt * 16 + l16) * 16 + q * 8) : zero8();
            acc[nt] = __builtin_amdgcn_mfma_f32_16x16x32_bf16(a, b, acc[nt], 0, 0, 0);
        }
#pragma unroll
        for (int nt = 0; nt < 8; ++nt) {
            int col = nt * 16 + l16;
            float bc = bias0[col];
#pragma unroll
            for (int r = 0; r < 4; ++r) {
                int rowL = wave * 16 + q * 4 + r;
                hb[rowL][col] = (__bf16)silu_f(acc[nt][r] + bc);
            }
        }
    }
    __syncthreads();
    // stage 2: Wh = h @ w_mlp1 + b1; msg = Wh * vhull[j]
    {
        v8bf af[4];
#pragma unroll
        for (int kt = 0; kt < 4; ++kt)
            af[kt] = *(const v8bf*)&hb[wave * 16 + l16][kt * 32 + q * 8];
        v4f acc[8];
#pragma unroll
        for (int i = 0; i < 8; ++i) acc[i] = zero4();
#pragma unroll
        for (int kt = 0; kt < 4; ++kt)
#pragma unroll
            for (int nt = 0; nt < 8; ++nt) {
                v8bf b = load8bf(w1T + (size_t)(nt * 16 + l16) * 128 + kt * 32 + q * 8);
                acc[nt] = __builtin_amdgcn_mfma_f32_16x16x32_bf16(af[kt], b, acc[nt], 0, 0, 0);
            }
#pragma unroll
        for (int nt = 0; nt < 8; ++nt) {
            int col = nt * 16 + l16;
            float bc = bias1[col];
#pragma unroll
            for (int r = 0; r < 4; ++r) {
                int rowL = wave * 16 + q * 4 + r;
                int slot = r0 + rowL;
                if (slot < EH) {
                    float wh = acc[nt][r] + bc;
                    int j = jb[rowL];
                    msg[(size_t)slot * 128 + col] = wh * (float)vhull[(size_t)j * 128 + col];
                }
            }
        }
    }
}

// ---------------- fused per-node MLP chain ----------------
__global__ __launch_bounds__(256, 2) void node_chain(
    const float* __restrict__ v, const float* __restrict__ oh,
    const __bf16* __restrict__ w1T, const float* __restrict__ b1,
    const __bf16* __restrict__ w2T, const float* __restrict__ b2,
    const __bf16* __restrict__ wcatT, const float* __restrict__ bcat,
    const __bf16* __restrict__ wupT, const float* __restrict__ bup,
    const __bf16* __restrict__ wl0T, const float* __restrict__ bl0,
    const __bf16* __restrict__ wl1T, const float* __restrict__ bl1,
    const float* __restrict__ wout, float* __restrict__ out, int M) {
    const int LD = 392;  // bf16 elements per LDS row (padded)
    __shared__ __bf16 buf[64 * 392];
    int t = threadIdx.x, wave = t >> 6, lane = t & 63, q = lane >> 4, l16 = lane & 15;
    int m0b = blockIdx.x * 64;
    int m0 = m0b + wave * 16;
    int arow = m0 + l16; if (arow >= M) arow = M - 1;

    // load v (fp32) -> cols 0..127, float4-vectorized
#pragma unroll
    for (int k = 0; k < 8; ++k) {
        int idx = t + k * 256;            // 2048 float4 total
        int row = idx >> 5, c4 = (idx & 31) * 4;
        int gr = m0b + row; if (gr >= M) gr = M - 1;
        float4 x = ((const float4*)(v + (size_t)gr * 128))[idx & 31];
        __bf16* p = &buf[row * LD + c4];
        p[0] = (__bf16)x.x; p[1] = (__bf16)x.y; p[2] = (__bf16)x.z; p[3] = (__bf16)x.w;
    }

    // stage0: h1 = silu(oh @ w1 + b1) [64,128] -> cols 256..383
    {
        v4f acc[8];
#pragma unroll
        for (int i = 0; i < 8; ++i) acc[i] = zero4();
#pragma unroll
        for (int kt = 0; kt < 4; ++kt) {
            v8bf a = load8f(oh + (size_t)arow * 128 + kt * 32 + q * 8);
#pragma unroll
            for (int nt = 0; nt < 8; ++nt) {
                v8bf b = load8bf(w1T + (size_t)(nt * 16 + l16) * 128 + kt * 32 + q * 8);
                acc[nt] = __builtin_amdgcn_mfma_f32_16x16x32_bf16(a, b, acc[nt], 0, 0, 0);
            }
        }
#pragma unroll
        for (int nt = 0; nt < 8; ++nt) {
            int col = nt * 16 + l16;
            float bc = b1[col];
#pragma unroll
            for (int r = 0; r < 4; ++r) {
                int rowL = wave * 16 + q * 4 + r;
                buf[rowL * LD + 256 + col] = (__bf16)silu_f(acc[nt][r] + bc);
            }
        }
    }
    __syncthreads();

    // stage1: l2v = h1 @ w2 + b2 [64,256] -> cols 128..383
    {
        v8bf af[4];
#pragma unroll
        for (int kt = 0; kt < 4; ++kt)
            af[kt] = *(const v8bf*)&buf[(wave * 16 + l16) * LD + 256 + kt * 32 + q * 8];
        __syncthreads();
        v4f acc[16];
#pragma unroll
        for (int i = 0; i < 16; ++i) acc[i] = zero4();
#pragma unroll
        for (int kt = 0; kt < 4; ++kt)
#pragma unroll
            for (int nt = 0; nt < 16; ++nt) {
                v8bf b = load8bf(w2T + (size_t)(nt * 16 + l16) * 128 + kt * 32 + q * 8);
                acc[nt] = __builtin_amdgcn_mfma_f32_16x16x32_bf16(af[kt], b, acc[nt], 0, 0, 0);
            }
#pragma unroll
        for (int nt = 0; nt < 16; ++nt) {
            int col = nt * 16 + l16;
            float bc = b2[col];
#pragma unroll
            for (int r = 0; r < 4; ++r) {
                int rowL = wave * 16 + q * 4 + r;
                buf[rowL * LD + 128 + col] = (__bf16)(acc[nt][r] + bc);
            }
        }
    }
    __syncthreads();

    // stage2: u = silu([v|l2v] @ wcat + bcat)  K=384 -> cols 0..127
    {
        v8bf af[12];
#pragma unroll
        for (int kt = 0; kt < 12; ++kt)
            af[kt] = *(const v8bf*)&buf[(wave * 16 + l16) * LD + kt * 32 + q * 8];
        __syncthreads();
        v4f acc[8];
#pragma unroll
        for (int i = 0; i < 8; ++i) acc[i] = zero4();
#pragma unroll
        for (int kt = 0; kt < 12; ++kt)
#pragma unroll
            for (int nt = 0; nt < 8; ++nt) {
                v8bf b = load8bf(wcatT + (size_t)(nt * 16 + l16) * 384 + kt * 32 + q * 8);
                acc[nt] = __builtin_amdgcn_mfma_f32_16x16x32_bf16(af[kt], b, acc[nt], 0, 0, 0);
            }
#pragma unroll
        for (int nt = 0; nt < 8; ++nt) {
            int col = nt * 16 + l16;
            float bc = bcat[col];
#pragma unroll
            for (int r = 0; r < 4; ++r) {
                int rowL = wave * 16 + q * 4 + r;
                buf[rowL * LD + col] = (__bf16)silu_f(acc[nt][r] + bc);
            }
        }
    }
    __syncthreads();

    // stage3: up = u @ wup + bup [64,256] -> cols 128..383 (no act)
    {
        v8bf af[4];
#pragma unroll
        for (int kt = 0; kt < 4; ++kt)
            af[kt] = *(const v8bf*)&buf[(wave * 16 + l16) * LD + kt * 32 + q * 8];
        __syncthreads();
        v4f acc[16];
#pragma unroll
        for (int i = 0; i < 16; ++i) acc[i] = zero4();
#pragma unroll
        for (int kt = 0; kt < 4; ++kt)
#pragma unroll
            for (int nt = 0; nt < 16; ++nt) {
                v8bf b = load8bf(wupT + (size_t)(nt * 16 + l16) * 128 + kt * 32 + q * 8);
                acc[nt] = __builtin_amdgcn_mfma_f32_16x16x32_bf16(af[kt], b, acc[nt], 0, 0, 0);
            }
#pragma unroll
        for (int nt = 0; nt < 16; ++nt) {
            int col = nt * 16 + l16;
            float bc = bup[col];
#pragma unroll
            for (int r = 0; r < 4; ++r) {
                int rowL = wave * 16 + q * 4 + r;
                buf[rowL * LD + 128 + col] = (__bf16)(acc[nt][r] + bc);
            }
        }
    }
    __syncthreads();

    // stage4 + stage5: a = silu(a @ W + b) with K=256, N=256, in-place cols 128..383
#pragma unroll
    for (int s = 0; s < 2; ++s) {
        const __bf16* wT = (s == 0) ? wl0T : wl1T;
        const float* bb = (s == 0) ? bl0 : bl1;
        v8bf af[8];
#pragma unroll
        for (int kt = 0; kt < 8; ++kt)
            af[kt] = *(const v8bf*)&buf[(wave * 16 + l16) * LD + 128 + kt * 32 + q * 8];
        __syncthreads();
        v4f acc[16];
#pragma unroll
        for (int i = 0; i < 16; ++i) acc[i] = zero4();
#pragma unroll
        for (int kt = 0; kt < 8; ++kt)
#pragma unroll
            for (int nt = 0; nt < 16; ++nt) {
                v8bf b = load8bf(wT + (size_t)(nt * 16 + l16) * 256 + kt * 32 + q * 8);
                acc[nt] = __builtin_amdgcn_mfma_f32_16x16x32_bf16(af[kt], b, acc[nt], 0, 0, 0);
            }
#pragma unroll
        for (int nt = 0; nt < 16; ++nt) {
            int col = nt * 16 + l16;
            float bc = bb[col];
#pragma unroll
            for (int r = 0; r < 4; ++r) {
                int rowL = wave * 16 + q * 4 + r;
                buf[rowL * LD + 128 + col] = (__bf16)silu_f(acc[nt][r] + bc);
            }
        }
        __syncthreads();
    }

    // stage6: out = a2 @ w_out  [256,1]
    if (t < 64) {
        float s = 0.f;
#pragma unroll 8
        for (int c = 0; c < 256; ++c)
            s += (float)buf[t * LD + 128 + c] * wout[c];
        int gr = m0b + t;
        if (gr < M) out[gr] = s;
    }
}

static inline char* align16(char* p) {
    return (char*)(((uintptr_t)p + 15) & ~(uintptr_t)15);
}

extern "C" void kernel_launch(void* const* d_in, const int* in_sizes, int n_in,
                              void* d_out, int out_size, void* d_ws, size_t ws_size,
                              hipStream_t stream) {
    const float* e2      = (const float*)d_in[0];
    const int*   iidx    = (const int*)d_in[1];
    const float* fea     = (const float*)d_in[2];
    const int*   eih     = (const int*)d_in[3];
    const float* w_hull  = (const float*)d_in[4];
    const float* w_mlp0  = (const float*)d_in[5];
    const float* b_mlp0  = (const float*)d_in[6];
    const float* w_mlp1  = (const float*)d_in[7];
    const float* b_mlp1  = (const float*)d_in[8];
    const float* w1_hull = (const float*)d_in[9];
    const float* b1_hull = (const float*)d_in[10];
    const float* w2_hull = (const float*)d_in[11];
    const float* b2_hull = (const float*)d_in[12];
    const float* w_cat   = (const float*)d_in[13];
    const float* b_cat   = (const float*)d_in[14];
    const float* w_up    = (const float*)d_in[15];
    const float* b_up    = (const float*)d_in[16];
    const float* w_l0    = (const float*)d_in[17];
    const float* b_l0    = (const float*)d_in[18];
    const float* w_l1    = (const float*)d_in[19];
    const float* b_l1    = (const float*)d_in[20];
    const float* w_out   = (const float*)d_in[21];

    int N  = out_size;           // OC = 1
    int E  = in_sizes[0] / 128;
    int EH = in_sizes[2] / 16;
    const int* jidx_h = eih;           // j_ = row 0
    const int* iidx_h = eih + EH;      // i_ = row 1 (scatter destination)

    char* p = (char*)d_ws;
    float* v  = (float*)p;  p += (size_t)N * 128 * 4;
    float* oh = (float*)p;  p += (size_t)N * 128 * 4;
    __bf16* vhull = (__bf16*)p; p += (size_t)N * 128 * 2;
    __bf16* wp = (__bf16*)p;
    __bf16* w_hullT = wp; wp += 128 * 128;
    __bf16* w0T     = wp; wp += 128 * 16;
    __bf16* w1mT    = wp; wp += 128 * 128;
    __bf16* w1hT    = wp; wp += 128 * 128;
    __bf16* w2hT    = wp; wp += 256 * 128;
    __bf16* wcatT   = wp; wp += 128 * 384;
    __bf16* wupT    = wp; wp += 256 * 128;
    __bf16* wl0T    = wp; wp += 256 * 256;
    __bf16* wl1T    = wp; wp += 256 * 256;
    p = align16((char*)wp);
    int* counts   = (int*)p; p += (size_t)N * 4;        // main-graph counts
    int* counts2  = (int*)p; p += (size_t)N * 4;        // hull counts (adjacent => one memset)
    int* row_s    = (int*)p; p += (size_t)(N + 1) * 4;
    int* cursor   = (int*)p; p += (size_t)N * 4;
    int* row2     = (int*)p; p += (size_t)(N + 1) * 4;
    int* cursor2  = (int*)p; p += (size_t)N * 4;
    int* order    = (int*)p; p += (size_t)E * 4;        // main-graph CSR edge order
    int* perm2    = (int*)p; p += (size_t)EH * 4;       // hull CSR edge order
    int* partials = (int*)p; p += 256 * 4;
    p = align16(p);
    // msg buffer: prefer ws; fall back to reusing e2's buffer (dead after gather_v)
    size_t need_msg = (size_t)EH * 128 * 4;
    float* msg;
    if ((size_t)(p - (char*)d_ws) + need_msg <= ws_size) msg = (float*)p;
    else                                                 msg = (float*)d_in[0];

    // transpose all weights to bf16 [N][K]
    transpose_w<<<(128 * 128 + 255) / 256, 256, 0, stream>>>(w_hull, w_hullT, 128, 128);
    transpose_w<<<(16 * 128 + 255) / 256, 256, 0, stream>>>(w_mlp0, w0T, 16, 128);
    transpose_w<<<(128 * 128 + 255) / 256, 256, 0, stream>>>(w_mlp1, w1mT, 128, 128);
    transpose_w<<<(128 * 128 + 255) / 256, 256, 0, stream>>>(w1_hull, w1hT, 128, 128);
    transpose_w<<<(128 * 256 + 255) / 256, 256, 0, stream>>>(w2_hull, w2hT, 128, 256);
    transpose_w<<<(384 * 128 + 255) / 256, 256, 0, stream>>>(w_cat, wcatT, 384, 128);
    transpose_w<<<(128 * 256 + 255) / 256, 256, 0, stream>>>(w_up, wupT, 128, 256);
    transpose_w<<<(256 * 256 + 255) / 256, 256, 0, stream>>>(w_l0, wl0T, 256, 256);
    transpose_w<<<(256 * 256 + 255) / 256, 256, 0, stream>>>(w_l1, wl1T, 256, 256);

    (void)hipMemsetAsync(counts, 0, (size_t)N * 4 * 2, stream);  // counts + counts2

    const int nbS = (N + 2047) / 2048;  // scan blocks

    // ---- main graph CSR ----
    hist_kernel<<<(E + 255) / 256, 256, 0, stream>>>(iidx, counts, E);
    scan_block_sums<<<nbS, 256, 0, stream>>>(counts, partials, N);
    scan_partials_serial<<<1, 64, 0, stream>>>(partials, nbS, row_s, N, E);
    scan_write<<<nbS, 256, 0, stream>>>(counts, partials, row_s, cursor, N);
    rank_scatter<<<(E + 255) / 256, 256, 0, stream>>>(iidx, cursor, order, E);

    // v = segment_sum(e2) by gather
    gather_v<<<(N + 1) / 2, 256, 0, stream>>>(e2, order, row_s, v, N);

    gemm_vhull<<<(N + 63) / 64, 256, 0, stream>>>(v, w_hullT, vhull, N);

    // ---- hull graph CSR ----
    hist_kernel<<<(EH + 255) / 256, 256, 0, stream>>>(iidx_h, counts2, EH);
    scan_block_sums<<<nbS, 256, 0, stream>>>(counts2, partials, N);
    scan_partials_serial<<<1, 64, 0, stream>>>(partials, nbS, row2, N, EH);
    scan_write<<<nbS, 256, 0, stream>>>(counts2, partials, row2, cursor2, N);
    rank_scatter<<<(EH + 255) / 256, 256, 0, stream>>>(iidx_h, cursor2, perm2, EH);

    // per-edge messages in CSR order (no atomics), then contiguous gather
    hull_msg<<<(EH + 63) / 64, 256, 0, stream>>>(fea, perm2, jidx_h, w0T, b_mlp0,
                                                 w1mT, b_mlp1, vhull, msg, EH);
    gather_oh<<<(N + 1) / 2, 256, 0, stream>>>(msg, row2, oh, N);

    node_chain<<<(N + 63) / 64, 256, 0, stream>>>(v, oh, w1hT, b1_hull, w2hT, b2_hull,
                                                  wcatT, b_cat, wupT, b_up,
                                                  wl0T, b_l0, wl1T, b_l1,
                                                  w_out, (float*)d_out, N);
}

// Round 4
// 1399.629 us; speedup vs baseline: 1.8957x; 1.2556x over previous
//
#include <hip/hip_runtime.h>
#include <hip/hip_bf16.h>

typedef __bf16 v8bf __attribute__((ext_vector_type(8)));
typedef float  v4f  __attribute__((ext_vector_type(4)));

__device__ __forceinline__ v8bf zero8() {
    v8bf r;
#pragma unroll
    for (int i = 0; i < 8; ++i) r[i] = (__bf16)0.f;
    return r;
}
__device__ __forceinline__ v4f zero4() { v4f r; r[0]=r[1]=r[2]=r[3]=0.f; return r; }

__device__ __forceinline__ v8bf load8bf(const __bf16* p) { return *(const v8bf*)p; }

__device__ __forceinline__ v8bf load8f(const float* p) {
    const float4 x = ((const float4*)p)[0];
    const float4 y = ((const float4*)p)[1];
    v8bf r;
    r[0]=(__bf16)x.x; r[1]=(__bf16)x.y; r[2]=(__bf16)x.z; r[3]=(__bf16)x.w;
    r[4]=(__bf16)y.x; r[5]=(__bf16)y.y; r[6]=(__bf16)y.z; r[7]=(__bf16)y.w;
    return r;
}
__device__ __forceinline__ float silu_f(float x) { return x / (1.f + __expf(-x)); }

// ---------------- fused weight transposes: fp32 [K][N] -> bf16 [N][K] ----------------
struct TDesc { const float* s; __bf16* d; int K; int N; };
struct TPack { TDesc t[9]; };

__global__ __launch_bounds__(256) void transpose_all(TPack p) {
    TDesc td = p.t[blockIdx.x];
    int total = td.K * td.N;
    for (int idx = blockIdx.y * 256 + threadIdx.x; idx < total; idx += 16 * 256) {
        int k = idx / td.N, n = idx - k * td.N;
        td.d[n * td.K + k] = (__bf16)td.s[idx];
    }
}

// ================= CSR construction (counting sort by destination) =================
__global__ __launch_bounds__(256) void hist_kernel(const int* __restrict__ idx,
                                                   int* __restrict__ counts, int n) {
    int g = blockIdx.x * 256 + threadIdx.x;
    if (g < n) atomicAdd(&counts[idx[g]], 1);
}

__global__ __launch_bounds__(256) void scan_block_sums(const int* __restrict__ counts,
                                                       int* __restrict__ partials, int n) {
    int t = threadIdx.x, b = blockIdx.x;
    int base = b * 2048 + t * 8;
    int s = 0;
#pragma unroll
    for (int i = 0; i < 8; ++i) {
        int g = base + i;
        s += (g < n) ? counts[g] : 0;
    }
#pragma unroll
    for (int off = 32; off; off >>= 1) s += __shfl_down(s, off);
    __shared__ int wsum[4];
    if ((t & 63) == 0) wsum[t >> 6] = s;
    __syncthreads();
    if (t == 0) partials[b] = wsum[0] + wsum[1] + wsum[2] + wsum[3];
}

__global__ void scan_partials_serial(int* __restrict__ partials, int nb,
                                     int* __restrict__ row_start, int n, int total) {
    if (threadIdx.x == 0) {
        int run = 0;
        for (int i = 0; i < nb; ++i) { int t = partials[i]; partials[i] = run; run += t; }
        row_start[n] = total;
    }
}

__global__ __launch_bounds__(256) void scan_write(const int* __restrict__ counts,
                                                  const int* __restrict__ partials,
                                                  int* __restrict__ row_start,
                                                  int* __restrict__ cursor, int n) {
    int t = threadIdx.x, b = blockIdx.x;
    int base = b * 2048 + t * 8;
    int vals[8];
    int tot = 0;
#pragma unroll
    for (int i = 0; i < 8; ++i) {
        int g = base + i;
        vals[i] = (g < n) ? counts[g] : 0;
        tot += vals[i];
    }
    __shared__ int sh[256];
    sh[t] = tot;
    __syncthreads();
#pragma unroll
    for (int d = 1; d < 256; d <<= 1) {
        int v = (t >= d) ? sh[t - d] : 0;
        __syncthreads();
        sh[t] += v;
        __syncthreads();
    }
    int run = partials[b] + sh[t] - tot;
#pragma unroll
    for (int i = 0; i < 8; ++i) {
        int g = base + i;
        if (g < n) { row_start[g] = run; cursor[g] = run; }
        run += vals[i];
    }
}

__global__ __launch_bounds__(256) void rank_scatter(const int* __restrict__ idx,
                                                    int* __restrict__ cursor,
                                                    int* __restrict__ order, int n) {
    int g = blockIdx.x * 256 + threadIdx.x;
    if (g < n) {
        int d = idx[g];
        int pos = atomicAdd(&cursor[d], 1);
        order[pos] = g;
    }
}

// ================= gather-reduce: v[node] = sum of e2 rows (CSR), bf16 out ==========
__global__ __launch_bounds__(256) void gather_v(const float* __restrict__ e2,
                                                const int* __restrict__ order,
                                                const int* __restrict__ row_start,
                                                __bf16* __restrict__ v, int N) {
    int t = threadIdx.x;
    int node = blockIdx.x * 2 + (t >> 7);
    int col = t & 127;
    if (node >= N) return;
    int r0 = row_start[node], r1 = row_start[node + 1];
    float acc = 0.f;
    for (int r = r0; r < r1; ++r) {
        int e = order[r];
        acc += e2[(size_t)e * 128 + col];
    }
    v[(size_t)node * 128 + col] = (__bf16)acc;
}

// msg rows contiguous per node (bf16)
__global__ __launch_bounds__(256) void gather_oh(const __bf16* __restrict__ msg,
                                                 const int* __restrict__ row_start,
                                                 __bf16* __restrict__ oh, int N) {
    int t = threadIdx.x;
    int node = blockIdx.x * 2 + (t >> 7);
    int col = t & 127;
    if (node >= N) return;
    int r0 = row_start[node], r1 = row_start[node + 1];
    float acc = 0.f;
    for (int r = r0; r < r1; ++r)
        acc += (float)msg[(size_t)r * 128 + col];
    oh[(size_t)node * 128 + col] = (__bf16)acc;
}

// ---------------- v_hull = v @ w_hull  [M,128]x[128,128], B in LDS ----------------
__global__ __launch_bounds__(256) void gemm_vhull(const __bf16* __restrict__ v,
                                                  const __bf16* __restrict__ wT,
                                                  __bf16* __restrict__ out, int M) {
    __shared__ __bf16 bS[128 * 136];   // stride 136 bf16 = 272 B (2-way, free)
    int t = threadIdx.x, wave = t >> 6, lane = t & 63, q = lane >> 4, l16 = lane & 15;
    int m0 = blockIdx.x * 128;
    {   // stage B once: 128 rows x 128 bf16, 2 threads/row
        int row = t >> 1, half = t & 1;
        const v8bf* g = (const v8bf*)(wT + (size_t)row * 128 + half * 64);
        v8bf* d = (v8bf*)(bS + row * 136 + half * 64);
#pragma unroll
        for (int i = 0; i < 8; ++i) d[i] = g[i];
    }
    __syncthreads();
    int r0 = m0 + wave * 32;
    v4f acc[2][8];
#pragma unroll
    for (int i = 0; i < 2; ++i)
#pragma unroll
        for (int j = 0; j < 8; ++j) acc[i][j] = zero4();
    int ar0 = r0 + l16;      if (ar0 >= M) ar0 = M - 1;
    int ar1 = r0 + 16 + l16; if (ar1 >= M) ar1 = M - 1;
#pragma unroll
    for (int kt = 0; kt < 4; ++kt) {
        v8bf a0 = load8bf(v + (size_t)ar0 * 128 + kt * 32 + q * 8);
        v8bf a1 = load8bf(v + (size_t)ar1 * 128 + kt * 32 + q * 8);
#pragma unroll
        for (int nt = 0; nt < 8; ++nt) {
            v8bf b = *(const v8bf*)(bS + (nt * 16 + l16) * 136 + kt * 32 + q * 8);
            acc[0][nt] = __builtin_amdgcn_mfma_f32_16x16x32_bf16(a0, b, acc[0][nt], 0, 0, 0);
            acc[1][nt] = __builtin_amdgcn_mfma_f32_16x16x32_bf16(a1, b, acc[1][nt], 0, 0, 0);
        }
    }
#pragma unroll
    for (int tile = 0; tile < 2; ++tile)
#pragma unroll
        for (int nt = 0; nt < 8; ++nt)
#pragma unroll
            for (int r = 0; r < 4; ++r) {
                int row = r0 + tile * 16 + q * 4 + r;
                if (row < M) out[(size_t)row * 128 + nt * 16 + l16] = (__bf16)acc[tile][nt][r];
            }
}

// -------- hull messages in CSR order: msg[slot] = vhull[j]*Wh (bf16 out) --------
__global__ __launch_bounds__(256) void hull_msg(const float* __restrict__ fea,
                                                const int* __restrict__ perm,
                                                const int* __restrict__ jidx,
                                                const __bf16* __restrict__ w0T,
                                                const float* __restrict__ bias0,
                                                const __bf16* __restrict__ w1T,
                                                const float* __restrict__ bias1,
                                                const __bf16* __restrict__ vhull,
                                                __bf16* __restrict__ msg, int EH) {
    __shared__ __bf16 hb[64][136];
    __shared__ int jb[64];
    int t = threadIdx.x;
    int wave = t >> 6, lane = t & 63, q = lane >> 4, l16 = lane & 15;
    int r0 = blockIdx.x * 64;
    if (t < 64) {
        int slot = r0 + t; if (slot >= EH) slot = EH - 1;
        jb[t] = jidx[perm[slot]];
    }
    {
        int slot = r0 + wave * 16 + l16; if (slot >= EH) slot = EH - 1;
        int e = perm[slot];
        v8bf a = (q < 2) ? load8f(fea + (size_t)e * 16 + q * 8) : zero8();
        v4f acc[8];
#pragma unroll
        for (int i = 0; i < 8; ++i) acc[i] = zero4();
#pragma unroll
        for (int nt = 0; nt < 8; ++nt) {
            v8bf b = (q < 2) ? load8bf(w0T + (size_t)(nt * 16 + l16) * 16 + q * 8) : zero8();
            acc[nt] = __builtin_amdgcn_mfma_f32_16x16x32_bf16(a, b, acc[nt], 0, 0, 0);
        }
#pragma unroll
        for (int nt = 0; nt < 8; ++nt) {
            int col = nt * 16 + l16;
            float bc = bias0[col];
#pragma unroll
            for (int r = 0; r < 4; ++r) {
                int rowL = wave * 16 + q * 4 + r;
                hb[rowL][col] = (__bf16)silu_f(acc[nt][r] + bc);
            }
        }
    }
    __syncthreads();
    {
        v8bf af[4];
#pragma unroll
        for (int kt = 0; kt < 4; ++kt)
            af[kt] = *(const v8bf*)&hb[wave * 16 + l16][kt * 32 + q * 8];
        v4f acc[8];
#pragma unroll
        for (int i = 0; i < 8; ++i) acc[i] = zero4();
#pragma unroll
        for (int kt = 0; kt < 4; ++kt)
#pragma unroll
            for (int nt = 0; nt < 8; ++nt) {
                v8bf b = load8bf(w1T + (size_t)(nt * 16 + l16) * 128 + kt * 32 + q * 8);
                acc[nt] = __builtin_amdgcn_mfma_f32_16x16x32_bf16(af[kt], b, acc[nt], 0, 0, 0);
            }
#pragma unroll
        for (int nt = 0; nt < 8; ++nt) {
            int col = nt * 16 + l16;
            float bc = bias1[col];
#pragma unroll
            for (int r = 0; r < 4; ++r) {
                int rowL = wave * 16 + q * 4 + r;
                int slot = r0 + rowL;
                if (slot < EH) {
                    float wh = acc[nt][r] + bc;
                    int j = jb[rowL];
                    msg[(size_t)slot * 128 + col] = (__bf16)(wh * (float)vhull[(size_t)j * 128 + col]);
                }
            }
        }
    }
}

// ================= fused per-node MLP chain v2 =================
// 128 rows/block, 32 rows/wave (wave owns its rows: no act barriers).
// B staged in LDS in 64-col chunks; whole-stage acc in VGPRs.
#define ALD 392   // act stride (bf16): 784 B == 4 dw mod 32 banks -> 2-way (free)
#define BLD 392   // B stride

template<int K, int NCH, bool SILU>
__device__ __forceinline__ void gemm_stage(const __bf16* __restrict__ wT,
                                           const float* __restrict__ bias,
                                           __bf16* actS, __bf16* bS,
                                           int srcCol, int dstCol,
                                           int wave, int lane, int t) {
    int q = lane >> 4, l16 = lane & 15;
    v4f acc[2][NCH * 4];
#pragma unroll
    for (int i = 0; i < 2; ++i)
#pragma unroll
        for (int j = 0; j < NCH * 4; ++j) acc[i][j] = zero4();

    int brow = t >> 2, sub = t & 3;   // 4 threads per B row (64 rows/chunk)
#pragma unroll
    for (int c = 0; c < NCH; ++c) {
        {   // stage B chunk c: rows = output cols c*64..c*64+63, each K bf16
            const v8bf* g = (const v8bf*)(wT + (size_t)(c * 64 + brow) * K) + sub * (K / 32);
            v8bf* d = (v8bf*)(bS + brow * BLD) + sub * (K / 32);
#pragma unroll
            for (int i = 0; i < K / 32; ++i) d[i] = g[i];
        }
        __syncthreads();
#pragma unroll
        for (int kt = 0; kt < K / 32; ++kt) {
            v8bf a0 = *(const v8bf*)(actS + (wave * 32 + l16) * ALD + srcCol + kt * 32 + q * 8);
            v8bf a1 = *(const v8bf*)(actS + (wave * 32 + 16 + l16) * ALD + srcCol + kt * 32 + q * 8);
#pragma unroll
            for (int nt = 0; nt < 4; ++nt) {
                v8bf b = *(const v8bf*)(bS + (nt * 16 + l16) * BLD + kt * 32 + q * 8);
                acc[0][c * 4 + nt] = __builtin_amdgcn_mfma_f32_16x16x32_bf16(a0, b, acc[0][c * 4 + nt], 0, 0, 0);
                acc[1][c * 4 + nt] = __builtin_amdgcn_mfma_f32_16x16x32_bf16(a1, b, acc[1][c * 4 + nt], 0, 0, 0);
            }
        }
        __syncthreads();
    }
    // epilogue: bias (+silu), write own rows (no barrier needed)
#pragma unroll
    for (int j = 0; j < NCH * 4; ++j) {
        float bc = bias[j * 16 + l16];
#pragma unroll
        for (int tile = 0; tile < 2; ++tile)
#pragma unroll
            for (int r = 0; r < 4; ++r) {
                int row = wave * 32 + tile * 16 + q * 4 + r;
                float val = acc[tile][j][r] + bc;
                if (SILU) val = silu_f(val);
                actS[row * ALD + dstCol + j * 16 + l16] = (__bf16)val;
            }
    }
}

__global__ __launch_bounds__(256, 1) void node_chain(
    const __bf16* __restrict__ v, const __bf16* __restrict__ oh,
    const __bf16* __restrict__ w1T, const float* __restrict__ b1,
    const __bf16* __restrict__ w2T, const float* __restrict__ b2,
    const __bf16* __restrict__ wcatT, const float* __restrict__ bcat,
    const __bf16* __restrict__ wupT, const float* __restrict__ bup,
    const __bf16* __restrict__ wl0T, const float* __restrict__ bl0,
    const __bf16* __restrict__ wl1T, const float* __restrict__ bl1,
    const float* __restrict__ wout, float* __restrict__ out, int M) {
    __shared__ __bf16 actS[128 * ALD];  // 100,352 B
    __shared__ __bf16 bS[64 * BLD];     //  50,176 B  (total 150,528 <= 160 KiB)
    int t = threadIdx.x, wave = t >> 6, lane = t & 63;
    int m0b = blockIdx.x * 128;

    // initial load (wave-owned rows): v -> cols [0,128), oh -> cols [256,384)
    {
        int row = wave * 32 + (lane >> 1), half = lane & 1;
        int gr = m0b + row; if (gr >= M) gr = M - 1;
        const v8bf* sv = (const v8bf*)(v + (size_t)gr * 128 + half * 64);
        const v8bf* so = (const v8bf*)(oh + (size_t)gr * 128 + half * 64);
        v8bf* dv = (v8bf*)(actS + row * ALD + half * 64);
        v8bf* doh = (v8bf*)(actS + row * ALD + 256 + half * 64);
#pragma unroll
        for (int i = 0; i < 8; ++i) { dv[i] = sv[i]; doh[i] = so[i]; }
    }
    // NOTE: no barrier needed for actS (wave-private rows); bS barriers are inside gemm_stage.

    // s0: h1 = silu(oh @ w1 + b1)          K=128 src 256 -> dst 128 (N=128)
    gemm_stage<128, 2, true >(w1T,  b1,   actS, bS, 256, 128, wave, lane, t);
    // s1: l2v = h1 @ w2 + b2               K=128 src 128 -> dst 128 (N=256)
    gemm_stage<128, 4, false>(w2T,  b2,   actS, bS, 128, 128, wave, lane, t);
    // s2: u = silu([v|l2v] @ wcat + bcat)  K=384 src 0   -> dst 0   (N=128)
    gemm_stage<384, 2, true >(wcatT, bcat, actS, bS, 0,   0,   wave, lane, t);
    // s3: up = u @ wup + bup               K=128 src 0   -> dst 128 (N=256)
    gemm_stage<128, 4, false>(wupT, bup,  actS, bS, 0,   128, wave, lane, t);
    // s4: a = silu(a @ wl0 + bl0)          K=256 in-place at 128 (N=256)
    gemm_stage<256, 4, true >(wl0T, bl0,  actS, bS, 128, 128, wave, lane, t);
    // s5: a = silu(a @ wl1 + bl1)
    gemm_stage<256, 4, true >(wl1T, bl1,  actS, bS, 128, 128, wave, lane, t);

    // s6: out = a @ w_out  (K=256 dot per row)
    {
        int row = wave * 32 + (lane >> 1), half = lane & 1;
        const __bf16* ap = actS + row * ALD + 128 + half * 128;
        const float* wp = wout + half * 128;
        float s = 0.f;
#pragma unroll
        for (int c8 = 0; c8 < 16; ++c8) {
            v8bf a8 = *(const v8bf*)(ap + c8 * 8);
            const float4 w0 = ((const float4*)(wp + c8 * 8))[0];
            const float4 w1 = ((const float4*)(wp + c8 * 8))[1];
            s += (float)a8[0] * w0.x + (float)a8[1] * w0.y + (float)a8[2] * w0.z + (float)a8[3] * w0.w;
            s += (float)a8[4] * w1.x + (float)a8[5] * w1.y + (float)a8[6] * w1.z + (float)a8[7] * w1.w;
        }
        s += __shfl_xor(s, 1);
        int gr = m0b + row;
        if (half == 0 && gr < M) out[gr] = s;
    }
}

static inline char* align16(char* p) {
    return (char*)(((uintptr_t)p + 15) & ~(uintptr_t)15);
}

extern "C" void kernel_launch(void* const* d_in, const int* in_sizes, int n_in,
                              void* d_out, int out_size, void* d_ws, size_t ws_size,
                              hipStream_t stream) {
    const float* e2      = (const float*)d_in[0];
    const int*   iidx    = (const int*)d_in[1];
    const float* fea     = (const float*)d_in[2];
    const int*   eih     = (const int*)d_in[3];
    const float* w_hull  = (const float*)d_in[4];
    const float* w_mlp0  = (const float*)d_in[5];
    const float* b_mlp0  = (const float*)d_in[6];
    const float* w_mlp1  = (const float*)d_in[7];
    const float* b_mlp1  = (const float*)d_in[8];
    const float* w1_hull = (const float*)d_in[9];
    const float* b1_hull = (const float*)d_in[10];
    const float* w2_hull = (const float*)d_in[11];
    const float* b2_hull = (const float*)d_in[12];
    const float* w_cat   = (const float*)d_in[13];
    const float* b_cat   = (const float*)d_in[14];
    const float* w_up    = (const float*)d_in[15];
    const float* b_up    = (const float*)d_in[16];
    const float* w_l0    = (const float*)d_in[17];
    const float* b_l0    = (const float*)d_in[18];
    const float* w_l1    = (const float*)d_in[19];
    const float* b_l1    = (const float*)d_in[20];
    const float* w_out   = (const float*)d_in[21];

    int N  = out_size;
    int E  = in_sizes[0] / 128;
    int EH = in_sizes[2] / 16;
    const int* jidx_h = eih;           // j_ = row 0
    const int* iidx_h = eih + EH;      // i_ = row 1 (scatter destination)

    char* p = (char*)d_ws;
    __bf16* v     = (__bf16*)p; p += (size_t)N * 128 * 2;
    __bf16* oh    = (__bf16*)p; p += (size_t)N * 128 * 2;
    __bf16* vhull = (__bf16*)p; p += (size_t)N * 128 * 2;
    __bf16* wp = (__bf16*)p;
    __bf16* w_hullT = wp; wp += 128 * 128;
    __bf16* w0T     = wp; wp += 128 * 16;
    __bf16* w1mT    = wp; wp += 128 * 128;
    __bf16* w1hT    = wp; wp += 128 * 128;
    __bf16* w2hT    = wp; wp += 256 * 128;
    __bf16* wcatT   = wp; wp += 128 * 384;
    __bf16* wupT    = wp; wp += 256 * 128;
    __bf16* wl0T    = wp; wp += 256 * 256;
    __bf16* wl1T    = wp; wp += 256 * 256;
    p = align16((char*)wp);
    int* counts   = (int*)p; p += (size_t)N * 4;
    int* counts2  = (int*)p; p += (size_t)N * 4;
    int* row_s    = (int*)p; p += (size_t)(N + 1) * 4;
    int* cursor   = (int*)p; p += (size_t)N * 4;
    int* row2     = (int*)p; p += (size_t)(N + 1) * 4;
    int* cursor2  = (int*)p; p += (size_t)N * 4;
    int* order    = (int*)p; p += (size_t)E * 4;
    int* perm2    = (int*)p; p += (size_t)EH * 4;
    int* partials = (int*)p; p += 256 * 4;
    p = align16(p);
    size_t need_msg = (size_t)EH * 128 * 2;
    __bf16* msg;
    if ((size_t)(p - (char*)d_ws) + need_msg <= ws_size) msg = (__bf16*)p;
    else                                                 msg = (__bf16*)d_in[0]; // e2 dead after gather_v; harness restores inputs

    // all 9 weight transposes in one dispatch
    TPack tp;
    tp.t[0] = { w_hull,  w_hullT, 128, 128 };
    tp.t[1] = { w_mlp0,  w0T,      16, 128 };
    tp.t[2] = { w_mlp1,  w1mT,    128, 128 };
    tp.t[3] = { w1_hull, w1hT,    128, 128 };
    tp.t[4] = { w2_hull, w2hT,    128, 256 };
    tp.t[5] = { w_cat,   wcatT,   384, 128 };
    tp.t[6] = { w_up,    wupT,    128, 256 };
    tp.t[7] = { w_l0,    wl0T,    256, 256 };
    tp.t[8] = { w_l1,    wl1T,    256, 256 };
    transpose_all<<<dim3(9, 16), 256, 0, stream>>>(tp);

    (void)hipMemsetAsync(counts, 0, (size_t)N * 4 * 2, stream);  // counts + counts2

    const int nbS = (N + 2047) / 2048;

    // ---- main graph CSR ----
    hist_kernel<<<(E + 255) / 256, 256, 0, stream>>>(iidx, counts, E);
    scan_block_sums<<<nbS, 256, 0, stream>>>(counts, partials, N);
    scan_partials_serial<<<1, 64, 0, stream>>>(partials, nbS, row_s, N, E);
    scan_write<<<nbS, 256, 0, stream>>>(counts, partials, row_s, cursor, N);
    rank_scatter<<<(E + 255) / 256, 256, 0, stream>>>(iidx, cursor, order, E);

    gather_v<<<(N + 1) / 2, 256, 0, stream>>>(e2, order, row_s, v, N);

    gemm_vhull<<<(N + 127) / 128, 256, 0, stream>>>(v, w_hullT, vhull, N);

    // ---- hull graph CSR ----
    hist_kernel<<<(EH + 255) / 256, 256, 0, stream>>>(iidx_h, counts2, EH);
    scan_block_sums<<<nbS, 256, 0, stream>>>(counts2, partials, N);
    scan_partials_serial<<<1, 64, 0, stream>>>(partials, nbS, row2, N, EH);
    scan_write<<<nbS, 256, 0, stream>>>(counts2, partials, row2, cursor2, N);
    rank_scatter<<<(EH + 255) / 256, 256, 0, stream>>>(iidx_h, cursor2, perm2, EH);

    hull_msg<<<(EH + 63) / 64, 256, 0, stream>>>(fea, perm2, jidx_h, w0T, b_mlp0,
                                                 w1mT, b_mlp1, vhull, msg, EH);
    gather_oh<<<(N + 1) / 2, 256, 0, stream>>>(msg, row2, oh, N);

    node_chain<<<(N + 127) / 128, 256, 0, stream>>>(v, oh, w1hT, b1_hull, w2hT, b2_hull,
                                                    wcatT, b_cat, wupT, b_up,
                                                    wl0T, b_l0, wl1T, b_l1,
                                                    w_out, (float*)d_out, N);
}

// Round 5
// 1140.900 us; speedup vs baseline: 2.3256x; 1.2268x over previous
//
#include <hip/hip_runtime.h>
#include <hip/hip_bf16.h>

typedef __bf16 v8bf __attribute__((ext_vector_type(8)));
typedef __bf16 v4bf __attribute__((ext_vector_type(4)));
typedef float  v4f  __attribute__((ext_vector_type(4)));

__device__ __forceinline__ v8bf zero8() {
    v8bf r;
#pragma unroll
    for (int i = 0; i < 8; ++i) r[i] = (__bf16)0.f;
    return r;
}
__device__ __forceinline__ v4f zero4() { v4f r; r[0]=r[1]=r[2]=r[3]=0.f; return r; }

__device__ __forceinline__ v8bf load8bf(const __bf16* p) { return *(const v8bf*)p; }

__device__ __forceinline__ v8bf load8f(const float* p) {
    const float4 x = ((const float4*)p)[0];
    const float4 y = ((const float4*)p)[1];
    v8bf r;
    r[0]=(__bf16)x.x; r[1]=(__bf16)x.y; r[2]=(__bf16)x.z; r[3]=(__bf16)x.w;
    r[4]=(__bf16)y.x; r[5]=(__bf16)y.y; r[6]=(__bf16)y.z; r[7]=(__bf16)y.w;
    return r;
}
__device__ __forceinline__ float silu_f(float x) { return x / (1.f + __expf(-x)); }

// ---------------- fused weight transposes: fp32 [K][N] -> bf16 [N][K] ----------------
struct TDesc { const float* s; __bf16* d; int K; int N; };
struct TPack { TDesc t[9]; };

__global__ __launch_bounds__(256) void transpose_all(TPack p) {
    TDesc td = p.t[blockIdx.x];
    int total = td.K * td.N;
    for (int idx = blockIdx.y * 256 + threadIdx.x; idx < total; idx += 16 * 256) {
        int k = idx / td.N, n = idx - k * td.N;
        td.d[n * td.K + k] = (__bf16)td.s[idx];
    }
}

// ================= CSR construction (counting sort by destination) =================
__global__ __launch_bounds__(256) void hist_kernel(const int* __restrict__ idx,
                                                   int* __restrict__ counts, int n) {
    int g = blockIdx.x * 256 + threadIdx.x;
    if (g < n) atomicAdd(&counts[idx[g]], 1);
}

__global__ __launch_bounds__(256) void scan_block_sums(const int* __restrict__ counts,
                                                       int* __restrict__ partials, int n) {
    int t = threadIdx.x, b = blockIdx.x;
    int base = b * 2048 + t * 8;
    int s = 0;
#pragma unroll
    for (int i = 0; i < 8; ++i) {
        int g = base + i;
        s += (g < n) ? counts[g] : 0;
    }
#pragma unroll
    for (int off = 32; off; off >>= 1) s += __shfl_down(s, off);
    __shared__ int wsum[4];
    if ((t & 63) == 0) wsum[t >> 6] = s;
    __syncthreads();
    if (t == 0) partials[b] = wsum[0] + wsum[1] + wsum[2] + wsum[3];
}

__global__ void scan_partials_serial(int* __restrict__ partials, int nb,
                                     int* __restrict__ row_start, int n, int total) {
    if (threadIdx.x == 0) {
        int run = 0;
        for (int i = 0; i < nb; ++i) { int t = partials[i]; partials[i] = run; run += t; }
        row_start[n] = total;
    }
}

__global__ __launch_bounds__(256) void scan_write(const int* __restrict__ counts,
                                                  const int* __restrict__ partials,
                                                  int* __restrict__ row_start,
                                                  int* __restrict__ cursor, int n) {
    int t = threadIdx.x, b = blockIdx.x;
    int base = b * 2048 + t * 8;
    int vals[8];
    int tot = 0;
#pragma unroll
    for (int i = 0; i < 8; ++i) {
        int g = base + i;
        vals[i] = (g < n) ? counts[g] : 0;
        tot += vals[i];
    }
    __shared__ int sh[256];
    sh[t] = tot;
    __syncthreads();
#pragma unroll
    for (int d = 1; d < 256; d <<= 1) {
        int v = (t >= d) ? sh[t - d] : 0;
        __syncthreads();
        sh[t] += v;
        __syncthreads();
    }
    int run = partials[b] + sh[t] - tot;
#pragma unroll
    for (int i = 0; i < 8; ++i) {
        int g = base + i;
        if (g < n) { row_start[g] = run; cursor[g] = run; }
        run += vals[i];
    }
}

__global__ __launch_bounds__(256) void rank_scatter(const int* __restrict__ idx,
                                                    int* __restrict__ cursor,
                                                    int* __restrict__ order, int n) {
    int g = blockIdx.x * 256 + threadIdx.x;
    if (g < n) {
        int d = idx[g];
        int pos = atomicAdd(&cursor[d], 1);
        order[pos] = g;
    }
}

// ===== gather-reduce v2: half-block/node, 4 edge-groups x 32 lanes x float4 =====
__global__ __launch_bounds__(256) void gather_v(const float* __restrict__ e2,
                                                const int* __restrict__ order,
                                                const int* __restrict__ row_start,
                                                __bf16* __restrict__ v, int N) {
    __shared__ float4 red[2][4][32];
    int t = threadIdx.x;
    int half = t >> 7, tl = t & 127;
    int grp = tl >> 5, lane = tl & 31;
    int node = blockIdx.x * 2 + half;
    int nc = (node < N) ? node : N - 1;
    int r0 = row_start[nc], r1 = row_start[nc + 1];
    float4 acc = make_float4(0.f, 0.f, 0.f, 0.f);
    int r = r0 + grp;
    for (; r + 4 < r1; r += 8) {   // 2 independent loads in flight per group
        int e0 = order[r], e1 = order[r + 4];
        float4 a = *(const float4*)(e2 + (size_t)e0 * 128 + lane * 4);
        float4 b = *(const float4*)(e2 + (size_t)e1 * 128 + lane * 4);
        acc.x += a.x + b.x; acc.y += a.y + b.y;
        acc.z += a.z + b.z; acc.w += a.w + b.w;
    }
    if (r < r1) {
        int e0 = order[r];
        float4 a = *(const float4*)(e2 + (size_t)e0 * 128 + lane * 4);
        acc.x += a.x; acc.y += a.y; acc.z += a.z; acc.w += a.w;
    }
    red[half][grp][lane] = acc;
    __syncthreads();
    if (grp == 0 && node < N) {
        float4 s0 = red[half][0][lane], s1 = red[half][1][lane];
        float4 s2 = red[half][2][lane], s3 = red[half][3][lane];
        v4bf o;
        o[0] = (__bf16)(s0.x + s1.x + s2.x + s3.x);
        o[1] = (__bf16)(s0.y + s1.y + s2.y + s3.y);
        o[2] = (__bf16)(s0.z + s1.z + s2.z + s3.z);
        o[3] = (__bf16)(s0.w + s1.w + s2.w + s3.w);
        *(v4bf*)(v + (size_t)node * 128 + lane * 4) = o;
    }
}

// ===== gather_oh v2: msg contiguous per node; 16 thr/node x v8bf =====
__global__ __launch_bounds__(256) void gather_oh(const __bf16* __restrict__ msg,
                                                 const int* __restrict__ row_start,
                                                 __bf16* __restrict__ oh, int N) {
    int t = threadIdx.x;
    int node = blockIdx.x * 16 + (t >> 4);
    int seg = t & 15;
    if (node >= N) return;
    int r0 = row_start[node], r1 = row_start[node + 1];
    float acc[8] = {0.f, 0.f, 0.f, 0.f, 0.f, 0.f, 0.f, 0.f};
    int r = r0;
    for (; r + 1 < r1; r += 2) {
        v8bf a = *(const v8bf*)(msg + (size_t)r * 128 + seg * 8);
        v8bf b = *(const v8bf*)(msg + (size_t)(r + 1) * 128 + seg * 8);
#pragma unroll
        for (int i = 0; i < 8; ++i) acc[i] += (float)a[i] + (float)b[i];
    }
    if (r < r1) {
        v8bf a = *(const v8bf*)(msg + (size_t)r * 128 + seg * 8);
#pragma unroll
        for (int i = 0; i < 8; ++i) acc[i] += (float)a[i];
    }
    v8bf o;
#pragma unroll
    for (int i = 0; i < 8; ++i) o[i] = (__bf16)acc[i];
    *(v8bf*)(oh + (size_t)node * 128 + seg * 8) = o;
}

// ---------------- v_hull = v @ w_hull  [M,128]x[128,128], B in LDS ----------------
__global__ __launch_bounds__(256) void gemm_vhull(const __bf16* __restrict__ v,
                                                  const __bf16* __restrict__ wT,
                                                  __bf16* __restrict__ out, int M) {
    __shared__ __bf16 bS[128 * 136];
    int t = threadIdx.x, wave = t >> 6, lane = t & 63, q = lane >> 4, l16 = lane & 15;
    int m0 = blockIdx.x * 128;
    {
        int row = t >> 1, half = t & 1;
        const v8bf* g = (const v8bf*)(wT + (size_t)row * 128 + half * 64);
        v8bf* d = (v8bf*)(bS + row * 136 + half * 64);
#pragma unroll
        for (int i = 0; i < 8; ++i) d[i] = g[i];
    }
    __syncthreads();
    int r0 = m0 + wave * 32;
    v4f acc[2][8];
#pragma unroll
    for (int i = 0; i < 2; ++i)
#pragma unroll
        for (int j = 0; j < 8; ++j) acc[i][j] = zero4();
    int ar0 = r0 + l16;      if (ar0 >= M) ar0 = M - 1;
    int ar1 = r0 + 16 + l16; if (ar1 >= M) ar1 = M - 1;
#pragma unroll
    for (int kt = 0; kt < 4; ++kt) {
        v8bf a0 = load8bf(v + (size_t)ar0 * 128 + kt * 32 + q * 8);
        v8bf a1 = load8bf(v + (size_t)ar1 * 128 + kt * 32 + q * 8);
#pragma unroll
        for (int nt = 0; nt < 8; ++nt) {
            v8bf b = *(const v8bf*)(bS + (nt * 16 + l16) * 136 + kt * 32 + q * 8);
            acc[0][nt] = __builtin_amdgcn_mfma_f32_16x16x32_bf16(a0, b, acc[0][nt], 0, 0, 0);
            acc[1][nt] = __builtin_amdgcn_mfma_f32_16x16x32_bf16(a1, b, acc[1][nt], 0, 0, 0);
        }
    }
#pragma unroll
    for (int tile = 0; tile < 2; ++tile)
#pragma unroll
        for (int nt = 0; nt < 8; ++nt)
#pragma unroll
            for (int r = 0; r < 4; ++r) {
                int row = r0 + tile * 16 + q * 4 + r;
                if (row < M) out[(size_t)row * 128 + nt * 16 + l16] = (__bf16)acc[tile][nt][r];
            }
}

// -------- hull messages in CSR order: msg[slot] = vhull[j]*Wh (bf16 out) --------
__global__ __launch_bounds__(256) void hull_msg(const float* __restrict__ fea,
                                                const int* __restrict__ perm,
                                                const int* __restrict__ jidx,
                                                const __bf16* __restrict__ w0T,
                                                const float* __restrict__ bias0,
                                                const __bf16* __restrict__ w1T,
                                                const float* __restrict__ bias1,
                                                const __bf16* __restrict__ vhull,
                                                __bf16* __restrict__ msg, int EH) {
    __shared__ __bf16 hb[64][136];
    __shared__ __bf16 whS[64][136];
    __shared__ int jb[64];
    int t = threadIdx.x;
    int wave = t >> 6, lane = t & 63, q = lane >> 4, l16 = lane & 15;
    int r0 = blockIdx.x * 64;
    if (t < 64) {
        int slot = r0 + t; if (slot >= EH) slot = EH - 1;
        jb[t] = jidx[perm[slot]];
    }
    {   // stage 1: h = silu(fea[e] @ w_mlp0 + b0), K=16 padded
        int slot = r0 + wave * 16 + l16; if (slot >= EH) slot = EH - 1;
        int e = perm[slot];
        v8bf a = (q < 2) ? load8f(fea + (size_t)e * 16 + q * 8) : zero8();
        v4f acc[8];
#pragma unroll
        for (int i = 0; i < 8; ++i) acc[i] = zero4();
#pragma unroll
        for (int nt = 0; nt < 8; ++nt) {
            v8bf b = (q < 2) ? load8bf(w0T + (size_t)(nt * 16 + l16) * 16 + q * 8) : zero8();
            acc[nt] = __builtin_amdgcn_mfma_f32_16x16x32_bf16(a, b, acc[nt], 0, 0, 0);
        }
#pragma unroll
        for (int nt = 0; nt < 8; ++nt) {
            int col = nt * 16 + l16;
            float bc = bias0[col];
#pragma unroll
            for (int r = 0; r < 4; ++r) {
                int rowL = wave * 16 + q * 4 + r;
                hb[rowL][col] = (__bf16)silu_f(acc[nt][r] + bc);
            }
        }
    }
    __syncthreads();
    {   // stage 2: Wh = h @ w_mlp1 + b1 -> whS
        v8bf af[4];
#pragma unroll
        for (int kt = 0; kt < 4; ++kt)
            af[kt] = *(const v8bf*)&hb[wave * 16 + l16][kt * 32 + q * 8];
        v4f acc[8];
#pragma unroll
        for (int i = 0; i < 8; ++i) acc[i] = zero4();
#pragma unroll
        for (int kt = 0; kt < 4; ++kt)
#pragma unroll
            for (int nt = 0; nt < 8; ++nt) {
                v8bf b = load8bf(w1T + (size_t)(nt * 16 + l16) * 128 + kt * 32 + q * 8);
                acc[nt] = __builtin_amdgcn_mfma_f32_16x16x32_bf16(af[kt], b, acc[nt], 0, 0, 0);
            }
#pragma unroll
        for (int nt = 0; nt < 8; ++nt) {
            int col = nt * 16 + l16;
            float bc = bias1[col];
#pragma unroll
            for (int r = 0; r < 4; ++r) {
                int rowL = wave * 16 + q * 4 + r;
                whS[rowL][col] = (__bf16)(acc[nt][r] + bc);
            }
        }
    }
    __syncthreads();
    {   // epilogue: vectorized vhull gather-multiply, coalesced msg write
        int row = t >> 2, sub = t & 3;
        int slot = r0 + row;
        if (slot < EH) {
            int j = jb[row];
            const v8bf* vr = (const v8bf*)(vhull + (size_t)j * 128 + sub * 32);
            v8bf* mp = (v8bf*)(msg + (size_t)slot * 128 + sub * 32);
#pragma unroll
            for (int i = 0; i < 4; ++i) {
                v8bf wv = *(const v8bf*)&whS[row][sub * 32 + i * 8];
                v8bf vv = vr[i];
                v8bf o;
#pragma unroll
                for (int k = 0; k < 8; ++k) o[k] = (__bf16)((float)wv[k] * (float)vv[k]);
                mp[i] = o;
            }
        }
    }
}

// ================= fused per-node MLP chain v3: 512 threads, 8 waves =================
// 128 rows/block, 16 rows/wave (wave owns rows: no act barriers).
#define ALD 392
#define BLD 392

template<int K, int NCH, bool SILU>
__device__ __forceinline__ void gemm_stage(const __bf16* __restrict__ wT,
                                           const float* __restrict__ bias,
                                           __bf16* actS, __bf16* bS,
                                           int srcCol, int dstCol,
                                           int wave, int lane, int t) {
    int q = lane >> 4, l16 = lane & 15;
    v4f acc[NCH * 4];
#pragma unroll
    for (int j = 0; j < NCH * 4; ++j) acc[j] = zero4();

    int brow = t >> 3, sub = t & 7;   // 8 threads per B row (64 rows/chunk)
#pragma unroll
    for (int c = 0; c < NCH; ++c) {
        {   // stage B chunk c (output cols c*64..c*64+63, K bf16 each)
            const v8bf* g = (const v8bf*)(wT + (size_t)(c * 64 + brow) * K) + sub * (K / 64);
            v8bf* d = (v8bf*)(bS + brow * BLD) + sub * (K / 64);
#pragma unroll
            for (int i = 0; i < K / 64; ++i) d[i] = g[i];
        }
        __syncthreads();
#pragma unroll
        for (int kt = 0; kt < K / 32; ++kt) {
            v8bf a0 = *(const v8bf*)(actS + (wave * 16 + l16) * ALD + srcCol + kt * 32 + q * 8);
#pragma unroll
            for (int nt = 0; nt < 4; ++nt) {
                v8bf b = *(const v8bf*)(bS + (nt * 16 + l16) * BLD + kt * 32 + q * 8);
                acc[c * 4 + nt] = __builtin_amdgcn_mfma_f32_16x16x32_bf16(a0, b, acc[c * 4 + nt], 0, 0, 0);
            }
        }
        __syncthreads();
    }
#pragma unroll
    for (int j = 0; j < NCH * 4; ++j) {
        float bc = bias[j * 16 + l16];
#pragma unroll
        for (int r = 0; r < 4; ++r) {
            int row = wave * 16 + q * 4 + r;
            float val = acc[j][r] + bc;
            if (SILU) val = silu_f(val);
            actS[row * ALD + dstCol + j * 16 + l16] = (__bf16)val;
        }
    }
}

__global__ __launch_bounds__(512, 1) void node_chain(
    const __bf16* __restrict__ v, const __bf16* __restrict__ oh,
    const __bf16* __restrict__ w1T, const float* __restrict__ b1,
    const __bf16* __restrict__ w2T, const float* __restrict__ b2,
    const __bf16* __restrict__ wcatT, const float* __restrict__ bcat,
    const __bf16* __restrict__ wupT, const float* __restrict__ bup,
    const __bf16* __restrict__ wl0T, const float* __restrict__ bl0,
    const __bf16* __restrict__ wl1T, const float* __restrict__ bl1,
    const float* __restrict__ wout, float* __restrict__ out, int M) {
    __shared__ __bf16 actS[128 * ALD];  // 100,352 B
    __shared__ __bf16 bS[64 * BLD];     //  50,176 B
    int t = threadIdx.x, wave = t >> 6, lane = t & 63;
    int m0b = blockIdx.x * 128;

    {   // initial load (wave-owned rows): v -> [0,128), oh -> [256,384)
        int row = wave * 16 + (lane >> 2), quarter = lane & 3;
        int gr = m0b + row; if (gr >= M) gr = M - 1;
        const v8bf* sv = (const v8bf*)(v + (size_t)gr * 128 + quarter * 32);
        const v8bf* so = (const v8bf*)(oh + (size_t)gr * 128 + quarter * 32);
        v8bf* dv = (v8bf*)(actS + row * ALD + quarter * 32);
        v8bf* doh = (v8bf*)(actS + row * ALD + 256 + quarter * 32);
#pragma unroll
        for (int i = 0; i < 4; ++i) { dv[i] = sv[i]; doh[i] = so[i]; }
    }
    // no actS barrier needed (wave-private rows); bS barriers inside gemm_stage

    gemm_stage<128, 2, true >(w1T,   b1,   actS, bS, 256, 128, wave, lane, t);
    gemm_stage<128, 4, false>(w2T,   b2,   actS, bS, 128, 128, wave, lane, t);
    gemm_stage<384, 2, true >(wcatT, bcat, actS, bS, 0,   0,   wave, lane, t);
    gemm_stage<128, 4, false>(wupT,  bup,  actS, bS, 0,   128, wave, lane, t);
    gemm_stage<256, 4, true >(wl0T,  bl0,  actS, bS, 128, 128, wave, lane, t);
    gemm_stage<256, 4, true >(wl1T,  bl1,  actS, bS, 128, 128, wave, lane, t);

    {   // out = a @ w_out (K=256 dot per row, 4 lanes/row)
        int row = wave * 16 + (lane >> 2), quarter = lane & 3;
        const __bf16* ap = actS + row * ALD + 128 + quarter * 64;
        const float* wq = wout + quarter * 64;
        float s = 0.f;
#pragma unroll
        for (int c8 = 0; c8 < 8; ++c8) {
            v8bf a8 = *(const v8bf*)(ap + c8 * 8);
            const float4 w0 = ((const float4*)(wq + c8 * 8))[0];
            const float4 w1 = ((const float4*)(wq + c8 * 8))[1];
            s += (float)a8[0] * w0.x + (float)a8[1] * w0.y + (float)a8[2] * w0.z + (float)a8[3] * w0.w;
            s += (float)a8[4] * w1.x + (float)a8[5] * w1.y + (float)a8[6] * w1.z + (float)a8[7] * w1.w;
        }
        s += __shfl_xor(s, 1);
        s += __shfl_xor(s, 2);
        int gr = m0b + row;
        if (quarter == 0 && gr < M) out[gr] = s;
    }
}

static inline char* align16(char* p) {
    return (char*)(((uintptr_t)p + 15) & ~(uintptr_t)15);
}

extern "C" void kernel_launch(void* const* d_in, const int* in_sizes, int n_in,
                              void* d_out, int out_size, void* d_ws, size_t ws_size,
                              hipStream_t stream) {
    const float* e2      = (const float*)d_in[0];
    const int*   iidx    = (const int*)d_in[1];
    const float* fea     = (const float*)d_in[2];
    const int*   eih     = (const int*)d_in[3];
    const float* w_hull  = (const float*)d_in[4];
    const float* w_mlp0  = (const float*)d_in[5];
    const float* b_mlp0  = (const float*)d_in[6];
    const float* w_mlp1  = (const float*)d_in[7];
    const float* b_mlp1  = (const float*)d_in[8];
    const float* w1_hull = (const float*)d_in[9];
    const float* b1_hull = (const float*)d_in[10];
    const float* w2_hull = (const float*)d_in[11];
    const float* b2_hull = (const float*)d_in[12];
    const float* w_cat   = (const float*)d_in[13];
    const float* b_cat   = (const float*)d_in[14];
    const float* w_up    = (const float*)d_in[15];
    const float* b_up    = (const float*)d_in[16];
    const float* w_l0    = (const float*)d_in[17];
    const float* b_l0    = (const float*)d_in[18];
    const float* w_l1    = (const float*)d_in[19];
    const float* b_l1    = (const float*)d_in[20];
    const float* w_out   = (const float*)d_in[21];

    int N  = out_size;
    int E  = in_sizes[0] / 128;
    int EH = in_sizes[2] / 16;
    const int* jidx_h = eih;           // j_ = row 0
    const int* iidx_h = eih + EH;      // i_ = row 1 (scatter destination)

    char* p = (char*)d_ws;
    __bf16* v     = (__bf16*)p; p += (size_t)N * 128 * 2;
    __bf16* oh    = (__bf16*)p; p += (size_t)N * 128 * 2;
    __bf16* vhull = (__bf16*)p; p += (size_t)N * 128 * 2;
    __bf16* wp = (__bf16*)p;
    __bf16* w_hullT = wp; wp += 128 * 128;
    __bf16* w0T     = wp; wp += 128 * 16;
    __bf16* w1mT    = wp; wp += 128 * 128;
    __bf16* w1hT    = wp; wp += 128 * 128;
    __bf16* w2hT    = wp; wp += 256 * 128;
    __bf16* wcatT   = wp; wp += 128 * 384;
    __bf16* wupT    = wp; wp += 256 * 128;
    __bf16* wl0T    = wp; wp += 256 * 256;
    __bf16* wl1T    = wp; wp += 256 * 256;
    p = align16((char*)wp);
    int* counts   = (int*)p; p += (size_t)N * 4;
    int* counts2  = (int*)p; p += (size_t)N * 4;
    int* row_s    = (int*)p; p += (size_t)(N + 1) * 4;
    int* cursor   = (int*)p; p += (size_t)N * 4;
    int* row2     = (int*)p; p += (size_t)(N + 1) * 4;
    int* cursor2  = (int*)p; p += (size_t)N * 4;
    int* order    = (int*)p; p += (size_t)E * 4;
    int* perm2    = (int*)p; p += (size_t)EH * 4;
    int* partials = (int*)p; p += 256 * 4;
    p = align16(p);
    size_t need_msg = (size_t)EH * 128 * 2;
    __bf16* msg;
    if ((size_t)(p - (char*)d_ws) + need_msg <= ws_size) msg = (__bf16*)p;
    else                                                 msg = (__bf16*)d_in[0]; // e2 dead after gather_v

    TPack tp;
    tp.t[0] = { w_hull,  w_hullT, 128, 128 };
    tp.t[1] = { w_mlp0,  w0T,      16, 128 };
    tp.t[2] = { w_mlp1,  w1mT,    128, 128 };
    tp.t[3] = { w1_hull, w1hT,    128, 128 };
    tp.t[4] = { w2_hull, w2hT,    128, 256 };
    tp.t[5] = { w_cat,   wcatT,   384, 128 };
    tp.t[6] = { w_up,    wupT,    128, 256 };
    tp.t[7] = { w_l0,    wl0T,    256, 256 };
    tp.t[8] = { w_l1,    wl1T,    256, 256 };
    transpose_all<<<dim3(9, 16), 256, 0, stream>>>(tp);

    (void)hipMemsetAsync(counts, 0, (size_t)N * 4 * 2, stream);

    const int nbS = (N + 2047) / 2048;

    // ---- main graph CSR ----
    hist_kernel<<<(E + 255) / 256, 256, 0, stream>>>(iidx, counts, E);
    scan_block_sums<<<nbS, 256, 0, stream>>>(counts, partials, N);
    scan_partials_serial<<<1, 64, 0, stream>>>(partials, nbS, row_s, N, E);
    scan_write<<<nbS, 256, 0, stream>>>(counts, partials, row_s, cursor, N);
    rank_scatter<<<(E + 255) / 256, 256, 0, stream>>>(iidx, cursor, order, E);

    gather_v<<<(N + 1) / 2, 256, 0, stream>>>(e2, order, row_s, v, N);

    gemm_vhull<<<(N + 127) / 128, 256, 0, stream>>>(v, w_hullT, vhull, N);

    // ---- hull graph CSR ----
    hist_kernel<<<(EH + 255) / 256, 256, 0, stream>>>(iidx_h, counts2, EH);
    scan_block_sums<<<nbS, 256, 0, stream>>>(counts2, partials, N);
    scan_partials_serial<<<1, 64, 0, stream>>>(partials, nbS, row2, N, EH);
    scan_write<<<nbS, 256, 0, stream>>>(counts2, partials, row2, cursor2, N);
    rank_scatter<<<(EH + 255) / 256, 256, 0, stream>>>(iidx_h, cursor2, perm2, EH);

    hull_msg<<<(EH + 63) / 64, 256, 0, stream>>>(fea, perm2, jidx_h, w0T, b_mlp0,
                                                 w1mT, b_mlp1, vhull, msg, EH);
    gather_oh<<<(N + 15) / 16, 256, 0, stream>>>(msg, row2, oh, N);

    node_chain<<<(N + 127) / 128, 512, 0, stream>>>(v, oh, w1hT, b1_hull, w2hT, b2_hull,
                                                    wcatT, b_cat, wupT, b_up,
                                                    wl0T, b_l0, wl1T, b_l1,
                                                    w_out, (float*)d_out, N);
}